// Round 9
// baseline (155.666 us; speedup 1.0000x reference)
//
#include <hip/hip_runtime.h>
#include <math.h>

#define BB 32
#define SS 256
#define DD 512
#define FF 1024
#define TT 5
#define K3 1536   // 3*D
#define K4 2048   // 4*D
#define GK 1536
#define SK 4      // split-K factor for gemm_v
#define KCH (GK / SK)   // 384

__device__ __forceinline__ float wave_reduce_sum(float x) {
#pragma unroll
  for (int o = 32; o > 0; o >>= 1) x += __shfl_xor(x, o);
  return x;
}

// exp-based tanh: ~8 instrs vs library tanhf's branchy range handling.
__device__ __forceinline__ float fast_tanh(float x) {
  float ax = fabsf(x);
  float t = __expf(-2.f * ax);
  float r = (1.f - t) / (1.f + t);
  return x < 0.f ? -r : r;
}

// ---------------- Kernel 0: bucket fragments, LENGTH-BALANCED per XCD ----
// lengths are sorted descending by b, so b-order striping gave XCD0 ~1.9x
// the row-work of XCD7. Folded grouping: XCD x <- sentences {x, 15-x,
// 16+x, 31-x} pairs long with short => per-XCD work balanced ~5%,
// still only 4 sentences (2 MB) per XCD's L2.
__global__ __launch_bounds__(1024)
void bucket_kernel(const int* __restrict__ fb, int* __restrict__ order) {
  __shared__ int cnt[BB];
  __shared__ int start[BB];
  int t = threadIdx.x;
  if (t < BB) cnt[t] = 0;
  __syncthreads();
  int b = fb[t];
  int r = atomicAdd(&cnt[b], 1);
  __syncthreads();
  if (t == 0) {
    int pos = 0;
    for (int x = 0; x < 8; ++x) {
      int sb[4] = {x, 15 - x, 16 + x, 31 - x};
      for (int j = 0; j < 4; ++j) { start[sb[j]] = pos; pos += cnt[sb[j]]; }
    }
  }
  __syncthreads();
  order[start[b] + r] = t;
}

// ---------------- Kernel A: span [F,1536] and c[F] (XCD-striped) ----------------
__global__ __launch_bounds__(128)
void span_kernel(const float* __restrict__ en, const int* __restrict__ fb,
                 const int* __restrict__ fs, const int* __restrict__ fe,
                 const float* __restrict__ att_b, const int* __restrict__ order,
                 float* __restrict__ span, float* __restrict__ cvec)
{
  int bid = blockIdx.x;
  int f = order[(bid & 7) * (FF / 8) + (bid >> 3)];
  int t = threadIdx.x;
  int b = fb[f], s = fs[f], e = fe[f];
  const float* base = en + (size_t)b * SS * DD;
  int d0 = t * 4;
  float4 lw = *(const float4*)(base + (size_t)s * DD + d0);
  float4 rw = *(const float4*)(base + (size_t)(e - 1) * DD + d0);
  float4 wsum = make_float4(0.f, 0.f, 0.f, 0.f);
  for (int p = s; p < e; ++p) {
    float4 m = *(const float4*)(base + (size_t)p * DD + d0);
    wsum.x += m.x; wsum.y += m.y; wsum.z += m.z; wsum.w += m.w;
  }
  float* sp = span + (size_t)f * K3;
  *(float4*)(sp + d0) = lw;
  *(float4*)(sp + DD + d0) = wsum;
  *(float4*)(sp + 2 * DD + d0) = rw;
  float4 a0 = *(const float4*)(att_b + d0);
  float4 a1 = *(const float4*)(att_b + DD + d0);
  float4 a2 = *(const float4*)(att_b + 2 * DD + d0);
  float part = lw.x*a0.x + lw.y*a0.y + lw.z*a0.z + lw.w*a0.w
             + wsum.x*a1.x + wsum.y*a1.y + wsum.z*a1.z + wsum.w*a1.w
             + rw.x*a2.x + rw.y*a2.y + rw.z*a2.z + rw.w*a2.w;
  part = wave_reduce_sum(part);
  __shared__ float red[2];
  if ((t & 63) == 0) red[t >> 6] = part;
  __syncthreads();
  if (t == 0) cvec[f] = red[0] + red[1];
}

// ---------------- Kernel B: v partials = span @ att_w, split-K ----------------
// BM=32 BN=64 BK=16, 256 threads, 2x4/thread, register prefetch.
// Grid (8,32,4)=1024 blocks -> 4 blocks/CU for latency hiding.
__global__ __launch_bounds__(256)
void gemm_v(const float* __restrict__ A,    // span [1024][1536]
            const float* __restrict__ Bw,   // att_w [1536][512]
            float* __restrict__ Cpart)      // [SK][1024][512]
{
  const int BM = 32, BN = 64, BK = 16;
  const int NIT = KCH / BK;   // 24
  __shared__ float As[BK][BM + 2];
  __shared__ float Bs[BK][BN + 4];
  int t = threadIdx.x;
  int n0 = blockIdx.x * BN;          // grid.x = 8
  int m0 = blockIdx.y * BM;          // grid.y = 32
  int kbase = blockIdx.z * KCH;

  int ar = t >> 3;          // 0..31  A row
  int ac = (t & 7) * 2;     // 0..14  A col pair
  int br = t >> 4;          // 0..15  B k-row
  int bc = (t & 15) * 4;    // 0..60
  int tm = (t >> 4) * 2;    // 0..30
  int tn = (t & 15) * 4;    // 0..60

  float acc[2][4] = {};

  const float* Aptr = A  + (size_t)(m0 + ar) * GK + kbase + ac;
  const float* Bptr = Bw + (size_t)(kbase + br) * DD + n0 + bc;

  float2 av = *(const float2*)(Aptr);
  float4 bv = *(const float4*)(Bptr);

  for (int it = 0; it < NIT; ++it) {
    __syncthreads();                 // previous compute done reading LDS
    As[ac][ar]     = av.x;
    As[ac + 1][ar] = av.y;
    *(float4*)(&Bs[br][bc]) = bv;
    __syncthreads();                 // stores visible
    if (it + 1 < NIT) {              // prefetch next tile (overlaps compute)
      av = *(const float2*)(Aptr + (it + 1) * BK);
      bv = *(const float4*)(Bptr + (size_t)(it + 1) * BK * DD);
    }
#pragma unroll
    for (int k = 0; k < BK; ++k) {
      float a0 = As[k][tm], a1 = As[k][tm + 1];
      float4 b = *(float4*)(&Bs[k][tn]);
      acc[0][0] += a0 * b.x; acc[0][1] += a0 * b.y; acc[0][2] += a0 * b.z; acc[0][3] += a0 * b.w;
      acc[1][0] += a1 * b.x; acc[1][1] += a1 * b.y; acc[1][2] += a1 * b.z; acc[1][3] += a1 * b.w;
    }
  }
  float* Cp = Cpart + (size_t)blockIdx.z * FF * DD;
#pragma unroll
  for (int i = 0; i < 2; ++i) {
    *(float4*)(Cp + (size_t)(m0 + tm + i) * DD + n0 + tn) =
        make_float4(acc[i][0], acc[i][1], acc[i][2], acc[i][3]);
  }
}

// ---------------- Kernel C: fused single-pass per-fragment ----------------
// Fixed-max softmax (tanh <= 1 => m = 1.0), row-skip past lengths[b],
// XCD-striped + length-balanced fragment order.
__global__ __launch_bounds__(256)
void frag_kernel(const float* __restrict__ en, const int* __restrict__ lengths,
                 const int* __restrict__ fb, const int* __restrict__ fs,
                 const int* __restrict__ fe,
                 const float* __restrict__ span, const float* __restrict__ cvec,
                 const float* __restrict__ vpart,
                 const float* __restrict__ tag_w, const float* __restrict__ tag_b,
                 const int* __restrict__ order,
                 float* __restrict__ out)
{
  __shared__ float v_lds[DD];
  __shared__ float buf[4][DD];
  __shared__ float wsum[4];
  __shared__ float mix_lds[DD];
  __shared__ float pl[4 * TT];
  __shared__ float l5[TT];

  int bid = blockIdx.x;
  int f = order[(bid & 7) * (FF / 8) + (bid >> 3)];
  int t = threadIdx.x;
  int lane = t & 63, wv = t >> 6;
  int b = fb[f], s = fs[f], e = fe[f];
  int lenb = lengths[b];
  float seqlen = (float)lengths[0];
  float invseq = 1.f / seqlen;
  float c = cvec[f];
  const float* mem = en + (size_t)b * SS * DD;

  if (t < 128) {
    float4 v0 = *(const float4*)(vpart + (size_t)f * DD + t * 4);
    float4 v1 = *(const float4*)(vpart + (size_t)FF * DD + (size_t)f * DD + t * 4);
    float4 v2 = *(const float4*)(vpart + 2 * (size_t)FF * DD + (size_t)f * DD + t * 4);
    float4 v3 = *(const float4*)(vpart + 3 * (size_t)FF * DD + (size_t)f * DD + t * 4);
    *(float4*)(v_lds + t * 4) = make_float4(v0.x + v1.x + v2.x + v3.x,
                                            v0.y + v1.y + v2.y + v3.y,
                                            v0.z + v1.z + v2.z + v3.z,
                                            v0.w + v1.w + v2.w + v3.w);
  }
  __syncthreads();

  float4 va = *(float4*)(v_lds + lane * 8);
  float4 vb = *(float4*)(v_lds + lane * 8 + 4);
  float ssum = 0.f;
  float am[8] = {0.f, 0.f, 0.f, 0.f, 0.f, 0.f, 0.f, 0.f};

  // rows this wave actually needs (p < lenb); wave-uniform
  int rows = lenb - wv * 64;
  if (rows > 64) rows = 64;
  for (int i0 = 0; i0 < rows; i0 += 8) {
    float4 R0[8], R1[8];
    float d8[8];
#pragma unroll
    for (int k = 0; k < 8; ++k) {
      if (i0 + k < rows) {
        int p = wv * 64 + i0 + k;
        const float* row = mem + (size_t)p * DD + lane * 8;
        R0[k] = *(const float4*)(row);
        R1[k] = *(const float4*)(row + 4);
        d8[k] = R0[k].x*va.x + R0[k].y*va.y + R0[k].z*va.z + R0[k].w*va.w
              + R1[k].x*vb.x + R1[k].y*vb.y + R1[k].z*vb.z + R1[k].w*vb.w;
      } else {
        d8[k] = 0.f;
      }
    }
#pragma unroll
    for (int o = 32; o > 0; o >>= 1) {
#pragma unroll
      for (int k = 0; k < 8; ++k) d8[k] += __shfl_xor(d8[k], o);
    }
#pragma unroll
    for (int k = 0; k < 8; ++k) {
      int p = wv * 64 + i0 + k;
      bool live = (i0 + k < rows) && !(p >= s && p < e);
      if (live) {
        float dis = (p < s) ? (float)(s - p) : (float)(p - e + 1);
        float pw = 1.f - dis * invseq;
        float sc = fast_tanh(pw * d8[k] + c);
        float u = __expf(sc - 1.f);       // fixed max = 1 (tanh bound)
        ssum += u;
        float upw = u * pw;
        am[0] += upw * R0[k].x; am[1] += upw * R0[k].y; am[2] += upw * R0[k].z; am[3] += upw * R0[k].w;
        am[4] += upw * R1[k].x; am[5] += upw * R1[k].y; am[6] += upw * R1[k].z; am[7] += upw * R1[k].w;
      }
    }
  }
  if (lane == 0) wsum[wv] = ssum;
  *(float4*)(&buf[wv][lane * 8])     = make_float4(am[0], am[1], am[2], am[3]);
  *(float4*)(&buf[wv][lane * 8 + 4]) = make_float4(am[4], am[5], am[6], am[7]);
  __syncthreads();
  {
    float S = wsum[0] + wsum[1] + wsum[2] + wsum[3];
    float inv = 1.f / S;
    int d0 = t * 2;
    mix_lds[d0]     = (buf[0][d0] + buf[1][d0] + buf[2][d0] + buf[3][d0]) * inv;
    mix_lds[d0 + 1] = (buf[0][d0 + 1] + buf[1][d0 + 1] + buf[2][d0 + 1] + buf[3][d0 + 1]) * inv;
  }
  __syncthreads();

  // ---- logits + log_softmax ----
  float vals[8];
  int idx = t * 8;
  if (idx < K3) {
    const float* sp = span + (size_t)f * K3 + idx;
    float4 x0 = *(const float4*)(sp);
    float4 x1 = *(const float4*)(sp + 4);
    vals[0]=x0.x; vals[1]=x0.y; vals[2]=x0.z; vals[3]=x0.w;
    vals[4]=x1.x; vals[5]=x1.y; vals[6]=x1.z; vals[7]=x1.w;
  } else {
#pragma unroll
    for (int j = 0; j < 8; ++j) vals[j] = mix_lds[idx - K3 + j];
  }
  float acc5[TT];
#pragma unroll
  for (int tg = 0; tg < TT; ++tg) {
    const float* twr = tag_w + (size_t)tg * K4 + idx;
    float a = 0.f;
#pragma unroll
    for (int j = 0; j < 8; ++j) a += vals[j] * twr[j];
    acc5[tg] = wave_reduce_sum(a);
  }
  if (lane == 0) {
#pragma unroll
    for (int tg = 0; tg < TT; ++tg) pl[wv * TT + tg] = acc5[tg];
  }
  __syncthreads();
  if (t < TT) {
    l5[t] = pl[t] + pl[TT + t] + pl[2 * TT + t] + pl[3 * TT + t] + tag_b[t];
  }
  __syncthreads();
  if (t == 0) {
    float mm = l5[0];
#pragma unroll
    for (int j = 1; j < TT; ++j) mm = fmaxf(mm, l5[j]);
    float se = 0.f;
#pragma unroll
    for (int j = 0; j < TT; ++j) se += __expf(l5[j] - mm);
    float lse = mm + logf(se);
#pragma unroll
    for (int j = 0; j < TT; ++j) out[(size_t)f * TT + j] = l5[j] - lse;
  }
}

extern "C" void kernel_launch(void* const* d_in, const int* in_sizes, int n_in,
                              void* d_out, int out_size, void* d_ws, size_t ws_size,
                              hipStream_t stream) {
  const float* en      = (const float*)d_in[0];
  const int*   lengths = (const int*)d_in[1];
  const int*   frag_b  = (const int*)d_in[2];
  const int*   frag_s  = (const int*)d_in[3];
  const int*   frag_e  = (const int*)d_in[4];
  const float* att_w   = (const float*)d_in[5];
  const float* att_b   = (const float*)d_in[6];
  const float* tag_w   = (const float*)d_in[7];
  const float* tag_b   = (const float*)d_in[8];
  float* out = (float*)d_out;

  float* span  = (float*)d_ws;                      // F*1536
  float* cvec  = span + (size_t)FF * K3;            // F
  float* vpart = cvec + FF;                         // SK*F*512
  int*   order = (int*)(vpart + (size_t)SK * FF * DD);  // F ints

  bucket_kernel<<<1, FF, 0, stream>>>(frag_b, order);
  span_kernel<<<FF, 128, 0, stream>>>(en, frag_b, frag_s, frag_e, att_b, order, span, cvec);
  gemm_v<<<dim3(8, 32, SK), 256, 0, stream>>>(span, att_w, vpart);
  frag_kernel<<<FF, 256, 0, stream>>>(en, lengths, frag_b, frag_s, frag_e,
                                      span, cvec, vpart, tag_w, tag_b, order, out);
}

// Round 12
// 146.381 us; speedup vs baseline: 1.0634x; 1.0634x over previous
//
#include <hip/hip_runtime.h>
#include <math.h>

#define BB 32
#define SS 256
#define DD 512
#define FF 1024
#define TT 5
#define K3 1536   // 3*D
#define K4 2048   // 4*D
#define GK 1536
#define SK 4      // split-K factor for gemm_v
#define KCH (GK / SK)   // 384

__device__ __forceinline__ float wave_reduce_sum(float x) {
#pragma unroll
  for (int o = 32; o > 0; o >>= 1) x += __shfl_xor(x, o);
  return x;
}

// Rotate-reduce within each 16-lane DPP row: after ror 1,2,4,8 every lane
// holds its 16-group sum. Pure VALU (v_mov_dpp) — relieves the LDS pipe
// that __shfl_xor's ds_swizzle/bpermute ops saturate.
__device__ __forceinline__ float row16_sum(float x) {
  int y;
  y = __builtin_amdgcn_mov_dpp(__float_as_int(x), 0x121, 0xf, 0xf, true); // ror:1
  x += __int_as_float(y);
  y = __builtin_amdgcn_mov_dpp(__float_as_int(x), 0x122, 0xf, 0xf, true); // ror:2
  x += __int_as_float(y);
  y = __builtin_amdgcn_mov_dpp(__float_as_int(x), 0x124, 0xf, 0xf, true); // ror:4
  x += __int_as_float(y);
  y = __builtin_amdgcn_mov_dpp(__float_as_int(x), 0x128, 0xf, 0xf, true); // ror:8
  x += __int_as_float(y);
  return x;
}

// exp-based tanh: ~8 instrs vs library tanhf's branchy range handling.
__device__ __forceinline__ float fast_tanh(float x) {
  float ax = fabsf(x);
  float t = __expf(-2.f * ax);
  float r = (1.f - t) / (1.f + t);
  return x < 0.f ? -r : r;
}

// ---------------- Kernel 0: bucket fragments, length-balanced per XCD ----
__global__ __launch_bounds__(1024)
void bucket_kernel(const int* __restrict__ fb, int* __restrict__ order) {
  __shared__ int cnt[BB];
  __shared__ int start[BB];
  int t = threadIdx.x;
  if (t < BB) cnt[t] = 0;
  __syncthreads();
  int b = fb[t];
  int r = atomicAdd(&cnt[b], 1);
  __syncthreads();
  if (t == 0) {
    int pos = 0;
    for (int x = 0; x < 8; ++x) {
      int sb[4] = {x, 15 - x, 16 + x, 31 - x};
      for (int j = 0; j < 4; ++j) { start[sb[j]] = pos; pos += cnt[sb[j]]; }
    }
  }
  __syncthreads();
  order[start[b] + r] = t;
}

// ---------------- Kernel A: span [F,1536] and c[F] (XCD-striped) ----------------
__global__ __launch_bounds__(128)
void span_kernel(const float* __restrict__ en, const int* __restrict__ fb,
                 const int* __restrict__ fs, const int* __restrict__ fe,
                 const float* __restrict__ att_b, const int* __restrict__ order,
                 float* __restrict__ span, float* __restrict__ cvec)
{
  int bid = blockIdx.x;
  int f = order[(bid & 7) * (FF / 8) + (bid >> 3)];
  int t = threadIdx.x;
  int b = fb[f], s = fs[f], e = fe[f];
  const float* base = en + (size_t)b * SS * DD;
  int d0 = t * 4;
  float4 lw = *(const float4*)(base + (size_t)s * DD + d0);
  float4 rw = *(const float4*)(base + (size_t)(e - 1) * DD + d0);
  float4 wsum = make_float4(0.f, 0.f, 0.f, 0.f);
  for (int p = s; p < e; ++p) {
    float4 m = *(const float4*)(base + (size_t)p * DD + d0);
    wsum.x += m.x; wsum.y += m.y; wsum.z += m.z; wsum.w += m.w;
  }
  float* sp = span + (size_t)f * K3;
  *(float4*)(sp + d0) = lw;
  *(float4*)(sp + DD + d0) = wsum;
  *(float4*)(sp + 2 * DD + d0) = rw;
  float4 a0 = *(const float4*)(att_b + d0);
  float4 a1 = *(const float4*)(att_b + DD + d0);
  float4 a2 = *(const float4*)(att_b + 2 * DD + d0);
  float part = lw.x*a0.x + lw.y*a0.y + lw.z*a0.z + lw.w*a0.w
             + wsum.x*a1.x + wsum.y*a1.y + wsum.z*a1.z + wsum.w*a1.w
             + rw.x*a2.x + rw.y*a2.y + rw.z*a2.z + rw.w*a2.w;
  part = wave_reduce_sum(part);
  __shared__ float red[2];
  if ((t & 63) == 0) red[t >> 6] = part;
  __syncthreads();
  if (t == 0) cvec[f] = red[0] + red[1];
}

// ---------------- Kernel B: v partials = span @ att_w, split-K ----------------
// Round-8 best: BM=64 BN=64 BK=16, 256 threads, 4x4/thread, register prefetch.
__global__ __launch_bounds__(256)
void gemm_v(const float* __restrict__ A,    // span [1024][1536]
            const float* __restrict__ Bw,   // att_w [1536][512]
            float* __restrict__ Cpart)      // [SK][1024][512]
{
  const int BM = 64, BN = 64, BK = 16;
  const int NIT = KCH / BK;   // 24
  __shared__ float As[BK][BM + 4];
  __shared__ float Bs[BK][BN + 4];
  int t = threadIdx.x;
  int n0 = blockIdx.x * BN;          // grid.x = 8
  int m0 = blockIdx.y * BM;          // grid.y = 16
  int kbase = blockIdx.z * KCH;

  int ar = t >> 2;          // 0..63  A row
  int ac = (t & 3) * 4;     // 0,4,8,12
  int br = t >> 4;          // 0..15  B k-row
  int bc = (t & 15) * 4;    // 0..60
  int tm = (t >> 4) * 4;    // 0..60
  int tn = (t & 15) * 4;    // 0..60

  float acc[4][4] = {};

  const float* Aptr = A  + (size_t)(m0 + ar) * GK + kbase + ac;
  const float* Bptr = Bw + (size_t)(kbase + br) * DD + n0 + bc;

  float4 av = *(const float4*)(Aptr);
  float4 bv = *(const float4*)(Bptr);

  for (int it = 0; it < NIT; ++it) {
    __syncthreads();                 // previous compute done reading LDS
    As[ac + 0][ar] = av.x;
    As[ac + 1][ar] = av.y;
    As[ac + 2][ar] = av.z;
    As[ac + 3][ar] = av.w;
    *(float4*)(&Bs[br][bc]) = bv;
    __syncthreads();                 // stores visible
    if (it + 1 < NIT) {              // prefetch next tile (overlaps compute)
      av = *(const float4*)(Aptr + (it + 1) * BK);
      bv = *(const float4*)(Bptr + (size_t)(it + 1) * BK * DD);
    }
#pragma unroll
    for (int k = 0; k < BK; ++k) {
      float4 a = *(float4*)(&As[k][tm]);
      float4 b = *(float4*)(&Bs[k][tn]);
      acc[0][0] += a.x * b.x; acc[0][1] += a.x * b.y; acc[0][2] += a.x * b.z; acc[0][3] += a.x * b.w;
      acc[1][0] += a.y * b.x; acc[1][1] += a.y * b.y; acc[1][2] += a.y * b.z; acc[1][3] += a.y * b.w;
      acc[2][0] += a.z * b.x; acc[2][1] += a.z * b.y; acc[2][2] += a.z * b.z; acc[2][3] += a.z * b.w;
      acc[3][0] += a.w * b.x; acc[3][1] += a.w * b.y; acc[3][2] += a.w * b.z; acc[3][3] += a.w * b.w;
    }
  }
  float* Cp = Cpart + (size_t)blockIdx.z * FF * DD;
#pragma unroll
  for (int i = 0; i < 4; ++i) {
    *(float4*)(Cp + (size_t)(m0 + tm + i) * DD + n0 + tn) =
        make_float4(acc[i][0], acc[i][1], acc[i][2], acc[i][3]);
  }
}

// ---------------- Kernel C: fused single-pass per-fragment ----------------
// Fixed-max softmax; row-skip past lengths[b]; DPP rotate-reduce (LDS-pipe
// ops per row: 6 -> 2).
__global__ __launch_bounds__(256)
void frag_kernel(const float* __restrict__ en, const int* __restrict__ lengths,
                 const int* __restrict__ fb, const int* __restrict__ fs,
                 const int* __restrict__ fe,
                 const float* __restrict__ span, const float* __restrict__ cvec,
                 const float* __restrict__ vpart,
                 const float* __restrict__ tag_w, const float* __restrict__ tag_b,
                 const int* __restrict__ order,
                 float* __restrict__ out)
{
  __shared__ float v_lds[DD];
  __shared__ float buf[4][DD];
  __shared__ float wsum[4];
  __shared__ float mix_lds[DD];
  __shared__ float pl[4 * TT];
  __shared__ float l5[TT];

  int bid = blockIdx.x;
  int f = order[(bid & 7) * (FF / 8) + (bid >> 3)];
  int t = threadIdx.x;
  int lane = t & 63, wv = t >> 6;
  int b = fb[f], s = fs[f], e = fe[f];
  int lenb = lengths[b];
  float seqlen = (float)lengths[0];
  float invseq = 1.f / seqlen;
  float c = cvec[f];
  const float* mem = en + (size_t)b * SS * DD;

  if (t < 128) {
    float4 v0 = *(const float4*)(vpart + (size_t)f * DD + t * 4);
    float4 v1 = *(const float4*)(vpart + (size_t)FF * DD + (size_t)f * DD + t * 4);
    float4 v2 = *(const float4*)(vpart + 2 * (size_t)FF * DD + (size_t)f * DD + t * 4);
    float4 v3 = *(const float4*)(vpart + 3 * (size_t)FF * DD + (size_t)f * DD + t * 4);
    *(float4*)(v_lds + t * 4) = make_float4(v0.x + v1.x + v2.x + v3.x,
                                            v0.y + v1.y + v2.y + v3.y,
                                            v0.z + v1.z + v2.z + v3.z,
                                            v0.w + v1.w + v2.w + v3.w);
  }
  __syncthreads();

  float4 va = *(float4*)(v_lds + lane * 8);
  float4 vb = *(float4*)(v_lds + lane * 8 + 4);
  float ssum = 0.f;
  float am[8] = {0.f, 0.f, 0.f, 0.f, 0.f, 0.f, 0.f, 0.f};

  // rows this wave actually needs (p < lenb); wave-uniform
  int rows = lenb - wv * 64;
  if (rows > 64) rows = 64;
  for (int i0 = 0; i0 < rows; i0 += 8) {
    float4 R0[8], R1[8];
    float d8[8];
#pragma unroll
    for (int k = 0; k < 8; ++k) {
      if (i0 + k < rows) {
        int p = wv * 64 + i0 + k;
        const float* row = mem + (size_t)p * DD + lane * 8;
        R0[k] = *(const float4*)(row);
        R1[k] = *(const float4*)(row + 4);
        d8[k] = R0[k].x*va.x + R0[k].y*va.y + R0[k].z*va.z + R0[k].w*va.w
              + R1[k].x*vb.x + R1[k].y*vb.y + R1[k].z*vb.z + R1[k].w*vb.w;
      } else {
        d8[k] = 0.f;
      }
    }
    // 16-lane DPP rotate-reduce (VALU), then 2 cross-group shuffles (LDS)
#pragma unroll
    for (int k = 0; k < 8; ++k) d8[k] = row16_sum(d8[k]);
#pragma unroll
    for (int k = 0; k < 8; ++k) d8[k] += __shfl_xor(d8[k], 16);
#pragma unroll
    for (int k = 0; k < 8; ++k) d8[k] += __shfl_xor(d8[k], 32);
#pragma unroll
    for (int k = 0; k < 8; ++k) {
      int p = wv * 64 + i0 + k;
      bool live = (i0 + k < rows) && !(p >= s && p < e);
      if (live) {
        float dis = (p < s) ? (float)(s - p) : (float)(p - e + 1);
        float pw = 1.f - dis * invseq;
        float sc = fast_tanh(pw * d8[k] + c);
        float u = __expf(sc - 1.f);       // fixed max = 1 (tanh bound)
        ssum += u;
        float upw = u * pw;
        am[0] += upw * R0[k].x; am[1] += upw * R0[k].y; am[2] += upw * R0[k].z; am[3] += upw * R0[k].w;
        am[4] += upw * R1[k].x; am[5] += upw * R1[k].y; am[6] += upw * R1[k].z; am[7] += upw * R1[k].w;
      }
    }
  }
  if (lane == 0) wsum[wv] = ssum;
  *(float4*)(&buf[wv][lane * 8])     = make_float4(am[0], am[1], am[2], am[3]);
  *(float4*)(&buf[wv][lane * 8 + 4]) = make_float4(am[4], am[5], am[6], am[7]);
  __syncthreads();
  {
    float S = wsum[0] + wsum[1] + wsum[2] + wsum[3];
    float inv = 1.f / S;
    int d0 = t * 2;
    mix_lds[d0]     = (buf[0][d0] + buf[1][d0] + buf[2][d0] + buf[3][d0]) * inv;
    mix_lds[d0 + 1] = (buf[0][d0 + 1] + buf[1][d0 + 1] + buf[2][d0 + 1] + buf[3][d0 + 1]) * inv;
  }
  __syncthreads();

  // ---- logits + log_softmax ----
  float vals[8];
  int idx = t * 8;
  if (idx < K3) {
    const float* sp = span + (size_t)f * K3 + idx;
    float4 x0 = *(const float4*)(sp);
    float4 x1 = *(const float4*)(sp + 4);
    vals[0]=x0.x; vals[1]=x0.y; vals[2]=x0.z; vals[3]=x0.w;
    vals[4]=x1.x; vals[5]=x1.y; vals[6]=x1.z; vals[7]=x1.w;
  } else {
#pragma unroll
    for (int j = 0; j < 8; ++j) vals[j] = mix_lds[idx - K3 + j];
  }
  float acc5[TT];
#pragma unroll
  for (int tg = 0; tg < TT; ++tg) {
    const float* twr = tag_w + (size_t)tg * K4 + idx;
    float a = 0.f;
#pragma unroll
    for (int j = 0; j < 8; ++j) a += vals[j] * twr[j];
    acc5[tg] = wave_reduce_sum(a);
  }
  if (lane == 0) {
#pragma unroll
    for (int tg = 0; tg < TT; ++tg) pl[wv * TT + tg] = acc5[tg];
  }
  __syncthreads();
  if (t < TT) {
    l5[t] = pl[t] + pl[TT + t] + pl[2 * TT + t] + pl[3 * TT + t] + tag_b[t];
  }
  __syncthreads();
  if (t == 0) {
    float mm = l5[0];
#pragma unroll
    for (int j = 1; j < TT; ++j) mm = fmaxf(mm, l5[j]);
    float se = 0.f;
#pragma unroll
    for (int j = 0; j < TT; ++j) se += __expf(l5[j] - mm);
    float lse = mm + logf(se);
#pragma unroll
    for (int j = 0; j < TT; ++j) out[(size_t)f * TT + j] = l5[j] - lse;
  }
}

extern "C" void kernel_launch(void* const* d_in, const int* in_sizes, int n_in,
                              void* d_out, int out_size, void* d_ws, size_t ws_size,
                              hipStream_t stream) {
  const float* en      = (const float*)d_in[0];
  const int*   lengths = (const int*)d_in[1];
  const int*   frag_b  = (const int*)d_in[2];
  const int*   frag_s  = (const int*)d_in[3];
  const int*   frag_e  = (const int*)d_in[4];
  const float* att_w   = (const float*)d_in[5];
  const float* att_b   = (const float*)d_in[6];
  const float* tag_w   = (const float*)d_in[7];
  const float* tag_b   = (const float*)d_in[8];
  float* out = (float*)d_out;

  float* span  = (float*)d_ws;                      // F*1536
  float* cvec  = span + (size_t)FF * K3;            // F
  float* vpart = cvec + FF;                         // SK*F*512
  int*   order = (int*)(vpart + (size_t)SK * FF * DD);  // F ints

  bucket_kernel<<<1, FF, 0, stream>>>(frag_b, order);
  span_kernel<<<FF, 128, 0, stream>>>(en, frag_b, frag_s, frag_e, att_b, order, span, cvec);
  gemm_v<<<dim3(8, 16, SK), 256, 0, stream>>>(span, att_w, vpart);
  frag_kernel<<<FF, 256, 0, stream>>>(en, lengths, frag_b, frag_s, frag_e,
                                      span, cvec, vpart, tag_w, tag_b, order, out);
}

// Round 15
// 146.000 us; speedup vs baseline: 1.0662x; 1.0026x over previous
//
#include <hip/hip_runtime.h>
#include <math.h>

#define BB 32
#define SS 256
#define DD 512
#define FF 1024
#define TT 5
#define K3 1536   // 3*D
#define K4 2048   // 4*D
#define GK 1536
#define SK 4      // split-K factor for gemm_v
#define KCH (GK / SK)   // 384

__device__ __forceinline__ float wave_reduce_sum(float x) {
#pragma unroll
  for (int o = 32; o > 0; o >>= 1) x += __shfl_xor(x, o);
  return x;
}

// Rotate-reduce within each 16-lane DPP row: pure VALU, off the LDS pipe.
__device__ __forceinline__ float row16_sum(float x) {
  int y;
  y = __builtin_amdgcn_mov_dpp(__float_as_int(x), 0x121, 0xf, 0xf, true); // ror:1
  x += __int_as_float(y);
  y = __builtin_amdgcn_mov_dpp(__float_as_int(x), 0x122, 0xf, 0xf, true); // ror:2
  x += __int_as_float(y);
  y = __builtin_amdgcn_mov_dpp(__float_as_int(x), 0x124, 0xf, 0xf, true); // ror:4
  x += __int_as_float(y);
  y = __builtin_amdgcn_mov_dpp(__float_as_int(x), 0x128, 0xf, 0xf, true); // ror:8
  x += __int_as_float(y);
  return x;
}

// exp-based tanh.
__device__ __forceinline__ float fast_tanh(float x) {
  float ax = fabsf(x);
  float t = __expf(-2.f * ax);
  float r = (1.f - t) / (1.f + t);
  return x < 0.f ? -r : r;
}

// ---------------- Kernel 0: bucket fragments, length-balanced per XCD ----
__global__ __launch_bounds__(1024)
void bucket_kernel(const int* __restrict__ fb, int* __restrict__ order) {
  __shared__ int cnt[BB];
  __shared__ int start[BB];
  int t = threadIdx.x;
  if (t < BB) cnt[t] = 0;
  __syncthreads();
  int b = fb[t];
  int r = atomicAdd(&cnt[b], 1);
  __syncthreads();
  if (t == 0) {
    int pos = 0;
    for (int x = 0; x < 8; ++x) {
      int sb[4] = {x, 15 - x, 16 + x, 31 - x};
      for (int j = 0; j < 4; ++j) { start[sb[j]] = pos; pos += cnt[sb[j]]; }
    }
  }
  __syncthreads();
  order[start[b] + r] = t;
}

// ---------------- Kernel A: span [F,1536] and c[F] (XCD-striped) ----------------
__global__ __launch_bounds__(128)
void span_kernel(const float* __restrict__ en, const int* __restrict__ fb,
                 const int* __restrict__ fs, const int* __restrict__ fe,
                 const float* __restrict__ att_b, const int* __restrict__ order,
                 float* __restrict__ span, float* __restrict__ cvec)
{
  int bid = blockIdx.x;
  int f = order[(bid & 7) * (FF / 8) + (bid >> 3)];
  int t = threadIdx.x;
  int b = fb[f], s = fs[f], e = fe[f];
  const float* base = en + (size_t)b * SS * DD;
  int d0 = t * 4;
  float4 lw = *(const float4*)(base + (size_t)s * DD + d0);
  float4 rw = *(const float4*)(base + (size_t)(e - 1) * DD + d0);
  float4 wsum = make_float4(0.f, 0.f, 0.f, 0.f);
  for (int p = s; p < e; ++p) {
    float4 m = *(const float4*)(base + (size_t)p * DD + d0);
    wsum.x += m.x; wsum.y += m.y; wsum.z += m.z; wsum.w += m.w;
  }
  float* sp = span + (size_t)f * K3;
  *(float4*)(sp + d0) = lw;
  *(float4*)(sp + DD + d0) = wsum;
  *(float4*)(sp + 2 * DD + d0) = rw;
  float4 a0 = *(const float4*)(att_b + d0);
  float4 a1 = *(const float4*)(att_b + DD + d0);
  float4 a2 = *(const float4*)(att_b + 2 * DD + d0);
  float part = lw.x*a0.x + lw.y*a0.y + lw.z*a0.z + lw.w*a0.w
             + wsum.x*a1.x + wsum.y*a1.y + wsum.z*a1.z + wsum.w*a1.w
             + rw.x*a2.x + rw.y*a2.y + rw.z*a2.z + rw.w*a2.w;
  part = wave_reduce_sum(part);
  __shared__ float red[2];
  if ((t & 63) == 0) red[t >> 6] = part;
  __syncthreads();
  if (t == 0) cvec[f] = red[0] + red[1];
}

// ---------------- Kernel B: v partials = span @ att_w, split-K ----------------
// Round-8 best: BM=64 BN=64 BK=16, 256 threads, 4x4/thread, register prefetch.
__global__ __launch_bounds__(256)
void gemm_v(const float* __restrict__ A,    // span [1024][1536]
            const float* __restrict__ Bw,   // att_w [1536][512]
            float* __restrict__ Cpart)      // [SK][1024][512]
{
  const int BM = 64, BN = 64, BK = 16;
  const int NIT = KCH / BK;   // 24
  __shared__ float As[BK][BM + 4];
  __shared__ float Bs[BK][BN + 4];
  int t = threadIdx.x;
  int n0 = blockIdx.x * BN;          // grid.x = 8
  int m0 = blockIdx.y * BM;          // grid.y = 16
  int kbase = blockIdx.z * KCH;

  int ar = t >> 2;          // 0..63  A row
  int ac = (t & 3) * 4;     // 0,4,8,12
  int br = t >> 4;          // 0..15  B k-row
  int bc = (t & 15) * 4;    // 0..60
  int tm = (t >> 4) * 4;    // 0..60
  int tn = (t & 15) * 4;    // 0..60

  float acc[4][4] = {};

  const float* Aptr = A  + (size_t)(m0 + ar) * GK + kbase + ac;
  const float* Bptr = Bw + (size_t)(kbase + br) * DD + n0 + bc;

  float4 av = *(const float4*)(Aptr);
  float4 bv = *(const float4*)(Bptr);

  for (int it = 0; it < NIT; ++it) {
    __syncthreads();                 // previous compute done reading LDS
    As[ac + 0][ar] = av.x;
    As[ac + 1][ar] = av.y;
    As[ac + 2][ar] = av.z;
    As[ac + 3][ar] = av.w;
    *(float4*)(&Bs[br][bc]) = bv;
    __syncthreads();                 // stores visible
    if (it + 1 < NIT) {              // prefetch next tile (overlaps compute)
      av = *(const float4*)(Aptr + (it + 1) * BK);
      bv = *(const float4*)(Bptr + (size_t)(it + 1) * BK * DD);
    }
#pragma unroll
    for (int k = 0; k < BK; ++k) {
      float4 a = *(float4*)(&As[k][tm]);
      float4 b = *(float4*)(&Bs[k][tn]);
      acc[0][0] += a.x * b.x; acc[0][1] += a.x * b.y; acc[0][2] += a.x * b.z; acc[0][3] += a.x * b.w;
      acc[1][0] += a.y * b.x; acc[1][1] += a.y * b.y; acc[1][2] += a.y * b.z; acc[1][3] += a.y * b.w;
      acc[2][0] += a.z * b.x; acc[2][1] += a.z * b.y; acc[2][2] += a.z * b.z; acc[2][3] += a.z * b.w;
      acc[3][0] += a.w * b.x; acc[3][1] += a.w * b.y; acc[3][2] += a.w * b.z; acc[3][3] += a.w * b.w;
    }
  }
  float* Cp = Cpart + (size_t)blockIdx.z * FF * DD;
#pragma unroll
  for (int i = 0; i < 4; ++i) {
    *(float4*)(Cp + (size_t)(m0 + tm + i) * DD + n0 + tn) =
        make_float4(acc[i][0], acc[i][1], acc[i][2], acc[i][3]);
  }
}

// ---------------- Kernel C: fused single-pass per-fragment ----------------
// launch_bounds(256, 4): grid is 1024 blocks = 4 blocks/CU = 4 waves/SIMD,
// so occupancy is GRID-limited — the default 8-wave register cap (64 VGPR,
// measured VGPR_Count=60) only forced the compiler to break the 8-row
// load batch (R0[8]+R1[8] = 64 VGPRs) into shallow groups, exposing L2
// latency. Min-4-waves/EU raises the cap to 128 VGPRs at zero occupancy
// cost: full 16-load batches stay in flight.
__global__ __launch_bounds__(256, 4)
void frag_kernel(const float* __restrict__ en, const int* __restrict__ lengths,
                 const int* __restrict__ fb, const int* __restrict__ fs,
                 const int* __restrict__ fe,
                 const float* __restrict__ span, const float* __restrict__ cvec,
                 const float* __restrict__ vpart,
                 const float* __restrict__ tag_w, const float* __restrict__ tag_b,
                 const int* __restrict__ order,
                 float* __restrict__ out)
{
  __shared__ float v_lds[DD];
  __shared__ float buf[4][DD];
  __shared__ float wsum[4];
  __shared__ float mix_lds[DD];
  __shared__ float pl[4 * TT];
  __shared__ float l5[TT];

  int bid = blockIdx.x;
  int f = order[(bid & 7) * (FF / 8) + (bid >> 3)];
  int t = threadIdx.x;
  int lane = t & 63, wv = t >> 6;
  int b = fb[f], s = fs[f], e = fe[f];
  int lenb = lengths[b];
  float seqlen = (float)lengths[0];
  float invseq = 1.f / seqlen;
  float c = cvec[f];
  const float* mem = en + (size_t)b * SS * DD;

  if (t < 128) {
    float4 v0 = *(const float4*)(vpart + (size_t)f * DD + t * 4);
    float4 v1 = *(const float4*)(vpart + (size_t)FF * DD + (size_t)f * DD + t * 4);
    float4 v2 = *(const float4*)(vpart + 2 * (size_t)FF * DD + (size_t)f * DD + t * 4);
    float4 v3 = *(const float4*)(vpart + 3 * (size_t)FF * DD + (size_t)f * DD + t * 4);
    *(float4*)(v_lds + t * 4) = make_float4(v0.x + v1.x + v2.x + v3.x,
                                            v0.y + v1.y + v2.y + v3.y,
                                            v0.z + v1.z + v2.z + v3.z,
                                            v0.w + v1.w + v2.w + v3.w);
  }
  __syncthreads();

  float4 va = *(float4*)(v_lds + lane * 8);
  float4 vb = *(float4*)(v_lds + lane * 8 + 4);
  float ssum = 0.f;
  float am[8] = {0.f, 0.f, 0.f, 0.f, 0.f, 0.f, 0.f, 0.f};

  // rows this wave actually needs (p < lenb); wave-uniform
  int rows = lenb - wv * 64;
  if (rows > 64) rows = 64;
  for (int i0 = 0; i0 < rows; i0 += 8) {
    float4 R0[8], R1[8];
    float d8[8];
#pragma unroll
    for (int k = 0; k < 8; ++k) {
      if (i0 + k < rows) {
        int p = wv * 64 + i0 + k;
        const float* row = mem + (size_t)p * DD + lane * 8;
        R0[k] = *(const float4*)(row);
        R1[k] = *(const float4*)(row + 4);
        d8[k] = R0[k].x*va.x + R0[k].y*va.y + R0[k].z*va.z + R0[k].w*va.w
              + R1[k].x*vb.x + R1[k].y*vb.y + R1[k].z*vb.z + R1[k].w*vb.w;
      } else {
        d8[k] = 0.f;
      }
    }
    // 16-lane DPP rotate-reduce (VALU), then 2 cross-group shuffles (LDS)
#pragma unroll
    for (int k = 0; k < 8; ++k) d8[k] = row16_sum(d8[k]);
#pragma unroll
    for (int k = 0; k < 8; ++k) d8[k] += __shfl_xor(d8[k], 16);
#pragma unroll
    for (int k = 0; k < 8; ++k) d8[k] += __shfl_xor(d8[k], 32);
#pragma unroll
    for (int k = 0; k < 8; ++k) {
      int p = wv * 64 + i0 + k;
      bool live = (i0 + k < rows) && !(p >= s && p < e);
      if (live) {
        float dis = (p < s) ? (float)(s - p) : (float)(p - e + 1);
        float pw = 1.f - dis * invseq;
        float sc = fast_tanh(pw * d8[k] + c);
        float u = __expf(sc - 1.f);       // fixed max = 1 (tanh bound)
        ssum += u;
        float upw = u * pw;
        am[0] += upw * R0[k].x; am[1] += upw * R0[k].y; am[2] += upw * R0[k].z; am[3] += upw * R0[k].w;
        am[4] += upw * R1[k].x; am[5] += upw * R1[k].y; am[6] += upw * R1[k].z; am[7] += upw * R1[k].w;
      }
    }
  }
  if (lane == 0) wsum[wv] = ssum;
  *(float4*)(&buf[wv][lane * 8])     = make_float4(am[0], am[1], am[2], am[3]);
  *(float4*)(&buf[wv][lane * 8 + 4]) = make_float4(am[4], am[5], am[6], am[7]);
  __syncthreads();
  {
    float S = wsum[0] + wsum[1] + wsum[2] + wsum[3];
    float inv = 1.f / S;
    int d0 = t * 2;
    mix_lds[d0]     = (buf[0][d0] + buf[1][d0] + buf[2][d0] + buf[3][d0]) * inv;
    mix_lds[d0 + 1] = (buf[0][d0 + 1] + buf[1][d0 + 1] + buf[2][d0 + 1] + buf[3][d0 + 1]) * inv;
  }
  __syncthreads();

  // ---- logits + log_softmax ----
  float vals[8];
  int idx = t * 8;
  if (idx < K3) {
    const float* sp = span + (size_t)f * K3 + idx;
    float4 x0 = *(const float4*)(sp);
    float4 x1 = *(const float4*)(sp + 4);
    vals[0]=x0.x; vals[1]=x0.y; vals[2]=x0.z; vals[3]=x0.w;
    vals[4]=x1.x; vals[5]=x1.y; vals[6]=x1.z; vals[7]=x1.w;
  } else {
#pragma unroll
    for (int j = 0; j < 8; ++j) vals[j] = mix_lds[idx - K3 + j];
  }
  float acc5[TT];
#pragma unroll
  for (int tg = 0; tg < TT; ++tg) {
    const float* twr = tag_w + (size_t)tg * K4 + idx;
    float a = 0.f;
#pragma unroll
    for (int j = 0; j < 8; ++j) a += vals[j] * twr[j];
    acc5[tg] = wave_reduce_sum(a);
  }
  if (lane == 0) {
#pragma unroll
    for (int tg = 0; tg < TT; ++tg) pl[wv * TT + tg] = acc5[tg];
  }
  __syncthreads();
  if (t < TT) {
    l5[t] = pl[t] + pl[TT + t] + pl[2 * TT + t] + pl[3 * TT + t] + tag_b[t];
  }
  __syncthreads();
  if (t == 0) {
    float mm = l5[0];
#pragma unroll
    for (int j = 1; j < TT; ++j) mm = fmaxf(mm, l5[j]);
    float se = 0.f;
#pragma unroll
    for (int j = 0; j < TT; ++j) se += __expf(l5[j] - mm);
    float lse = mm + logf(se);
#pragma unroll
    for (int j = 0; j < TT; ++j) out[(size_t)f * TT + j] = l5[j] - lse;
  }
}

extern "C" void kernel_launch(void* const* d_in, const int* in_sizes, int n_in,
                              void* d_out, int out_size, void* d_ws, size_t ws_size,
                              hipStream_t stream) {
  const float* en      = (const float*)d_in[0];
  const int*   lengths = (const int*)d_in[1];
  const int*   frag_b  = (const int*)d_in[2];
  const int*   frag_s  = (const int*)d_in[3];
  const int*   frag_e  = (const int*)d_in[4];
  const float* att_w   = (const float*)d_in[5];
  const float* att_b   = (const float*)d_in[6];
  const float* tag_w   = (const float*)d_in[7];
  const float* tag_b   = (const float*)d_in[8];
  float* out = (float*)d_out;

  float* span  = (float*)d_ws;                      // F*1536
  float* cvec  = span + (size_t)FF * K3;            // F
  float* vpart = cvec + FF;                         // SK*F*512
  int*   order = (int*)(vpart + (size_t)SK * FF * DD);  // F ints

  bucket_kernel<<<1, FF, 0, stream>>>(frag_b, order);
  span_kernel<<<FF, 128, 0, stream>>>(en, frag_b, frag_s, frag_e, att_b, order, span, cvec);
  gemm_v<<<dim3(8, 16, SK), 256, 0, stream>>>(span, att_w, vpart);
  frag_kernel<<<FF, 256, 0, stream>>>(en, lengths, frag_b, frag_s, frag_e,
                                      span, cvec, vpart, tag_w, tag_b, order, out);
}

// Round 16
// 130.895 us; speedup vs baseline: 1.1892x; 1.1154x over previous
//
#include <hip/hip_runtime.h>
#include <math.h>

#define BB 32
#define SS 256
#define DD 512
#define FF 1024
#define TT 5
#define K3 1536   // 3*D
#define K4 2048   // 4*D
#define GK 1536
#define SK 4      // split-K factor for gemm_v
#define KCH (GK / SK)   // 384

__device__ __forceinline__ float wave_reduce_sum(float x) {
#pragma unroll
  for (int o = 32; o > 0; o >>= 1) x += __shfl_xor(x, o);
  return x;
}

// Rotate-reduce within each 16-lane DPP row: pure VALU. After ror 1,2,4,8
// every lane holds its 16-lane group's sum.
__device__ __forceinline__ float row16_sum(float x) {
  int y;
  y = __builtin_amdgcn_mov_dpp(__float_as_int(x), 0x121, 0xf, 0xf, true); // ror:1
  x += __int_as_float(y);
  y = __builtin_amdgcn_mov_dpp(__float_as_int(x), 0x122, 0xf, 0xf, true); // ror:2
  x += __int_as_float(y);
  y = __builtin_amdgcn_mov_dpp(__float_as_int(x), 0x124, 0xf, 0xf, true); // ror:4
  x += __int_as_float(y);
  y = __builtin_amdgcn_mov_dpp(__float_as_int(x), 0x128, 0xf, 0xf, true); // ror:8
  x += __int_as_float(y);
  return x;
}

// exp-based tanh.
__device__ __forceinline__ float fast_tanh(float x) {
  float ax = fabsf(x);
  float t = __expf(-2.f * ax);
  float r = (1.f - t) / (1.f + t);
  return x < 0.f ? -r : r;
}

// ---------------- Kernel 0: bucket fragments, length-balanced per XCD ----
__global__ __launch_bounds__(1024)
void bucket_kernel(const int* __restrict__ fb, int* __restrict__ order) {
  __shared__ int cnt[BB];
  __shared__ int start[BB];
  int t = threadIdx.x;
  if (t < BB) cnt[t] = 0;
  __syncthreads();
  int b = fb[t];
  int r = atomicAdd(&cnt[b], 1);
  __syncthreads();
  if (t == 0) {
    int pos = 0;
    for (int x = 0; x < 8; ++x) {
      int sb[4] = {x, 15 - x, 16 + x, 31 - x};
      for (int j = 0; j < 4; ++j) { start[sb[j]] = pos; pos += cnt[sb[j]]; }
    }
  }
  __syncthreads();
  order[start[b] + r] = t;
}

// ---------------- Kernel A: span [F,1536] and c[F] (XCD-striped) ----------------
__global__ __launch_bounds__(128)
void span_kernel(const float* __restrict__ en, const int* __restrict__ fb,
                 const int* __restrict__ fs, const int* __restrict__ fe,
                 const float* __restrict__ att_b, const int* __restrict__ order,
                 float* __restrict__ span, float* __restrict__ cvec)
{
  int bid = blockIdx.x;
  int f = order[(bid & 7) * (FF / 8) + (bid >> 3)];
  int t = threadIdx.x;
  int b = fb[f], s = fs[f], e = fe[f];
  const float* base = en + (size_t)b * SS * DD;
  int d0 = t * 4;
  float4 lw = *(const float4*)(base + (size_t)s * DD + d0);
  float4 rw = *(const float4*)(base + (size_t)(e - 1) * DD + d0);
  float4 wsum = make_float4(0.f, 0.f, 0.f, 0.f);
  for (int p = s; p < e; ++p) {
    float4 m = *(const float4*)(base + (size_t)p * DD + d0);
    wsum.x += m.x; wsum.y += m.y; wsum.z += m.z; wsum.w += m.w;
  }
  float* sp = span + (size_t)f * K3;
  *(float4*)(sp + d0) = lw;
  *(float4*)(sp + DD + d0) = wsum;
  *(float4*)(sp + 2 * DD + d0) = rw;
  float4 a0 = *(const float4*)(att_b + d0);
  float4 a1 = *(const float4*)(att_b + DD + d0);
  float4 a2 = *(const float4*)(att_b + 2 * DD + d0);
  float part = lw.x*a0.x + lw.y*a0.y + lw.z*a0.z + lw.w*a0.w
             + wsum.x*a1.x + wsum.y*a1.y + wsum.z*a1.z + wsum.w*a1.w
             + rw.x*a2.x + rw.y*a2.y + rw.z*a2.z + rw.w*a2.w;
  part = wave_reduce_sum(part);
  __shared__ float red[2];
  if ((t & 63) == 0) red[t >> 6] = part;
  __syncthreads();
  if (t == 0) cvec[f] = red[0] + red[1];
}

// ---------------- Kernel B: v partials = span @ att_w, split-K ----------------
// Round-8 best: BM=64 BN=64 BK=16, 256 threads, 4x4/thread, register prefetch.
__global__ __launch_bounds__(256)
void gemm_v(const float* __restrict__ A,    // span [1024][1536]
            const float* __restrict__ Bw,   // att_w [1536][512]
            float* __restrict__ Cpart)      // [SK][1024][512]
{
  const int BM = 64, BN = 64, BK = 16;
  const int NIT = KCH / BK;   // 24
  __shared__ float As[BK][BM + 4];
  __shared__ float Bs[BK][BN + 4];
  int t = threadIdx.x;
  int n0 = blockIdx.x * BN;          // grid.x = 8
  int m0 = blockIdx.y * BM;          // grid.y = 16
  int kbase = blockIdx.z * KCH;

  int ar = t >> 2;          // 0..63  A row
  int ac = (t & 3) * 4;     // 0,4,8,12
  int br = t >> 4;          // 0..15  B k-row
  int bc = (t & 15) * 4;    // 0..60
  int tm = (t >> 4) * 4;    // 0..60
  int tn = (t & 15) * 4;    // 0..60

  float acc[4][4] = {};

  const float* Aptr = A  + (size_t)(m0 + ar) * GK + kbase + ac;
  const float* Bptr = Bw + (size_t)(kbase + br) * DD + n0 + bc;

  float4 av = *(const float4*)(Aptr);
  float4 bv = *(const float4*)(Bptr);

  for (int it = 0; it < NIT; ++it) {
    __syncthreads();                 // previous compute done reading LDS
    As[ac + 0][ar] = av.x;
    As[ac + 1][ar] = av.y;
    As[ac + 2][ar] = av.z;
    As[ac + 3][ar] = av.w;
    *(float4*)(&Bs[br][bc]) = bv;
    __syncthreads();                 // stores visible
    if (it + 1 < NIT) {              // prefetch next tile (overlaps compute)
      av = *(const float4*)(Aptr + (it + 1) * BK);
      bv = *(const float4*)(Bptr + (size_t)(it + 1) * BK * DD);
    }
#pragma unroll
    for (int k = 0; k < BK; ++k) {
      float4 a = *(float4*)(&As[k][tm]);
      float4 b = *(float4*)(&Bs[k][tn]);
      acc[0][0] += a.x * b.x; acc[0][1] += a.x * b.y; acc[0][2] += a.x * b.z; acc[0][3] += a.x * b.w;
      acc[1][0] += a.y * b.x; acc[1][1] += a.y * b.y; acc[1][2] += a.y * b.z; acc[1][3] += a.y * b.w;
      acc[2][0] += a.z * b.x; acc[2][1] += a.z * b.y; acc[2][2] += a.z * b.z; acc[2][3] += a.z * b.w;
      acc[3][0] += a.w * b.x; acc[3][1] += a.w * b.y; acc[3][2] += a.w * b.z; acc[3][3] += a.w * b.w;
    }
  }
  float* Cp = Cpart + (size_t)blockIdx.z * FF * DD;
#pragma unroll
  for (int i = 0; i < 4; ++i) {
    *(float4*)(Cp + (size_t)(m0 + tm + i) * DD + n0 + tn) =
        make_float4(acc[i][0], acc[i][1], acc[i][2], acc[i][3]);
  }
}

// ---------------- Kernel C: fused single-pass per-fragment ----------------
// GROUP-PER-ROW layout: each 16-lane group owns one row; lane j holds dims
// {q*64 + j*4 .. +4 : q=0..7} (32 dims) of the row, the matching v-chunk,
// and the matching am-chunk — ALL in registers. The dot reduce is a single
// row16_sum (pure DPP); zero ds_bpermute in the main loop; the staged row
// stays live for the am accumulation (no L1 reload — the R15 finding:
// VGPR_Count=60 proved the compiler reloads rather than keep 64 regs live).
// Tail (tanh/exp/pw) computed once per 4 rows via predication.
__global__ __launch_bounds__(256, 4)
void frag_kernel(const float* __restrict__ en, const int* __restrict__ lengths,
                 const int* __restrict__ fb, const int* __restrict__ fs,
                 const int* __restrict__ fe,
                 const float* __restrict__ span, const float* __restrict__ cvec,
                 const float* __restrict__ vpart,
                 const float* __restrict__ tag_w, const float* __restrict__ tag_b,
                 const int* __restrict__ order,
                 float* __restrict__ out)
{
  __shared__ float v_lds[DD];
  __shared__ float buf[16][DD];   // 16 group-partials (4 waves x 4 groups)
  __shared__ float wsum[16];
  __shared__ float mix_lds[DD];
  __shared__ float pl[4 * TT];
  __shared__ float l5[TT];

  int bid = blockIdx.x;
  int f = order[(bid & 7) * (FF / 8) + (bid >> 3)];
  int t = threadIdx.x;
  int lane = t & 63, wv = t >> 6;
  int g = lane >> 4;          // group 0..3 within wave
  int j = lane & 15;          // lane within group
  int b = fb[f], s = fs[f], e = fe[f];
  int lenb = lengths[b];
  float seqlen = (float)lengths[0];
  float invseq = 1.f / seqlen;
  float c = cvec[f];
  const float* mem = en + (size_t)b * SS * DD;

  if (t < 128) {
    float4 v0 = *(const float4*)(vpart + (size_t)f * DD + t * 4);
    float4 v1 = *(const float4*)(vpart + (size_t)FF * DD + (size_t)f * DD + t * 4);
    float4 v2 = *(const float4*)(vpart + 2 * (size_t)FF * DD + (size_t)f * DD + t * 4);
    float4 v3 = *(const float4*)(vpart + 3 * (size_t)FF * DD + (size_t)f * DD + t * 4);
    *(float4*)(v_lds + t * 4) = make_float4(v0.x + v1.x + v2.x + v3.x,
                                            v0.y + v1.y + v2.y + v3.y,
                                            v0.z + v1.z + v2.z + v3.z,
                                            v0.w + v1.w + v2.w + v3.w);
  }
  __syncthreads();

  // this lane's 32-dim slice of v (8 x float4 at q*64 + j*4)
  float4 vr[8];
#pragma unroll
  for (int q = 0; q < 8; ++q) vr[q] = *(float4*)(v_lds + q * 64 + j * 4);

  float4 am8[8];
#pragma unroll
  for (int q = 0; q < 8; ++q) am8[q] = make_float4(0.f, 0.f, 0.f, 0.f);
  float ssum = 0.f;

  int rows = lenb - wv * 64;
  if (rows > 64) rows = 64;
  if (rows < 0) rows = 0;

  for (int i0 = 0; i0 < rows; i0 += 4) {
    int r = wv * 64 + i0 + g;              // this group's row (always < 256)
    const float* row = mem + (size_t)r * DD;
    float4 st[8];
    float part = 0.f;
#pragma unroll
    for (int q = 0; q < 8; ++q) {
      st[q] = *(const float4*)(row + q * 64 + j * 4);
      part += st[q].x * vr[q].x + st[q].y * vr[q].y
            + st[q].z * vr[q].z + st[q].w * vr[q].w;
    }
    float d = row16_sum(part);             // full 512-dim dot, all 16 lanes
    bool live = (i0 + g < rows) && !(r >= s && r < e);
    float dis = (r < s) ? (float)(s - r) : (float)(r - e + 1);
    float pw = 1.f - dis * invseq;
    float sc = fast_tanh(pw * d + c);
    float u = live ? __expf(sc - 1.f) : 0.f;   // fixed max = 1 (tanh bound)
    ssum += u;
    float upw = u * pw;
#pragma unroll
    for (int q = 0; q < 8; ++q) {
      am8[q].x += upw * st[q].x;
      am8[q].y += upw * st[q].y;
      am8[q].z += upw * st[q].z;
      am8[q].w += upw * st[q].w;
    }
  }

  int part_id = wv * 4 + g;   // 0..15
  if (j == 0) wsum[part_id] = ssum;        // identical across the group
#pragma unroll
  for (int q = 0; q < 8; ++q)
    *(float4*)(&buf[part_id][q * 64 + j * 4]) = am8[q];
  __syncthreads();

  {
    float S = 0.f;
#pragma unroll
    for (int i = 0; i < 16; ++i) S += wsum[i];
    float inv = 1.f / S;
    int d0 = t * 2;
    float a0 = 0.f, a1 = 0.f;
#pragma unroll
    for (int i = 0; i < 16; ++i) { a0 += buf[i][d0]; a1 += buf[i][d0 + 1]; }
    mix_lds[d0]     = a0 * inv;
    mix_lds[d0 + 1] = a1 * inv;
  }
  __syncthreads();

  // ---- logits + log_softmax ----
  float vals[8];
  int idx = t * 8;
  if (idx < K3) {
    const float* sp = span + (size_t)f * K3 + idx;
    float4 x0 = *(const float4*)(sp);
    float4 x1 = *(const float4*)(sp + 4);
    vals[0]=x0.x; vals[1]=x0.y; vals[2]=x0.z; vals[3]=x0.w;
    vals[4]=x1.x; vals[5]=x1.y; vals[6]=x1.z; vals[7]=x1.w;
  } else {
#pragma unroll
    for (int jj = 0; jj < 8; ++jj) vals[jj] = mix_lds[idx - K3 + jj];
  }
  float acc5[TT];
#pragma unroll
  for (int tg = 0; tg < TT; ++tg) {
    const float* twr = tag_w + (size_t)tg * K4 + idx;
    float a = 0.f;
#pragma unroll
    for (int jj = 0; jj < 8; ++jj) a += vals[jj] * twr[jj];
    acc5[tg] = wave_reduce_sum(a);
  }
  if (lane == 0) {
#pragma unroll
    for (int tg = 0; tg < TT; ++tg) pl[wv * TT + tg] = acc5[tg];
  }
  __syncthreads();
  if (t < TT) {
    l5[t] = pl[t] + pl[TT + t] + pl[2 * TT + t] + pl[3 * TT + t] + tag_b[t];
  }
  __syncthreads();
  if (t == 0) {
    float mm = l5[0];
#pragma unroll
    for (int jj = 1; jj < TT; ++jj) mm = fmaxf(mm, l5[jj]);
    float se = 0.f;
#pragma unroll
    for (int jj = 0; jj < TT; ++jj) se += __expf(l5[jj] - mm);
    float lse = mm + logf(se);
#pragma unroll
    for (int jj = 0; jj < TT; ++jj) out[(size_t)f * TT + jj] = l5[jj] - lse;
  }
}

extern "C" void kernel_launch(void* const* d_in, const int* in_sizes, int n_in,
                              void* d_out, int out_size, void* d_ws, size_t ws_size,
                              hipStream_t stream) {
  const float* en      = (const float*)d_in[0];
  const int*   lengths = (const int*)d_in[1];
  const int*   frag_b  = (const int*)d_in[2];
  const int*   frag_s  = (const int*)d_in[3];
  const int*   frag_e  = (const int*)d_in[4];
  const float* att_w   = (const float*)d_in[5];
  const float* att_b   = (const float*)d_in[6];
  const float* tag_w   = (const float*)d_in[7];
  const float* tag_b   = (const float*)d_in[8];
  float* out = (float*)d_out;

  float* span  = (float*)d_ws;                      // F*1536
  float* cvec  = span + (size_t)FF * K3;            // F
  float* vpart = cvec + FF;                         // SK*F*512
  int*   order = (int*)(vpart + (size_t)SK * FF * DD);  // F ints

  bucket_kernel<<<1, FF, 0, stream>>>(frag_b, order);
  span_kernel<<<FF, 128, 0, stream>>>(en, frag_b, frag_s, frag_e, att_b, order, span, cvec);
  gemm_v<<<dim3(8, 16, SK), 256, 0, stream>>>(span, att_w, vpart);
  frag_kernel<<<FF, 256, 0, stream>>>(en, lengths, frag_b, frag_s, frag_e,
                                      span, cvec, vpart, tag_w, tag_b, order, out);
}